// Round 1
// baseline (238.978 us; speedup 1.0000x reference)
//
#include <hip/hip_runtime.h>
#include <math.h>

// RX gate on qubit 5 of 12, batch 4096 states of dim 4096.
// out = state @ (c*I - i*s*X_hyd)  with X_hyd pairing index i <-> i^64.
// Pure element-wise butterfly -> memory-bound streaming kernel.
//
// Layout: d_in[0]=state_re [4096*4096 f32], d_in[1]=state_im, d_in[2]=theta [1 f32].
// d_out = [out_re (16M floats) | out_im (16M floats)].

#define NQ_N 4096
#define NQ_BATCH 4096
#define PARTNER_BIT 64            // i ^ 64 flips qubit 5 (kron(I_32, X, I_64))
#define VEC_PARTNER 16            // in float4-index space: 64/4

__global__ __launch_bounds__(256)
void rx_butterfly_kernel(const float4* __restrict__ sr,
                         const float4* __restrict__ si,
                         const float*  __restrict__ theta_p,
                         float4* __restrict__ out_re,
                         float4* __restrict__ out_im)
{
    // scalar broadcast load; cached after first wave
    const float half = 0.5f * theta_p[0];
    const float c = cosf(half);
    const float s = sinf(half);

    // pair index over float4 elements: total vecs = BATCH*N/4 = 2^22, pairs = 2^21
    const unsigned p = blockIdx.x * blockDim.x + threadIdx.x;
    // expand: insert a 0 at bit 4 -> low member of the pair; partner = |16
    const unsigned v = ((p >> 4) << 5) | (p & 15u);
    const unsigned w = v | VEC_PARTNER;

    const float4 srL = sr[v];
    const float4 srH = sr[w];
    const float4 siL = si[v];
    const float4 siH = si[w];

    float4 reL, reH, imL, imH;
    reL.x = fmaf(c, srL.x, s * siH.x);
    reL.y = fmaf(c, srL.y, s * siH.y);
    reL.z = fmaf(c, srL.z, s * siH.z);
    reL.w = fmaf(c, srL.w, s * siH.w);

    reH.x = fmaf(c, srH.x, s * siL.x);
    reH.y = fmaf(c, srH.y, s * siL.y);
    reH.z = fmaf(c, srH.z, s * siL.z);
    reH.w = fmaf(c, srH.w, s * siL.w);

    imL.x = fmaf(c, siL.x, -s * srH.x);
    imL.y = fmaf(c, siL.y, -s * srH.y);
    imL.z = fmaf(c, siL.z, -s * srH.z);
    imL.w = fmaf(c, siL.w, -s * srH.w);

    imH.x = fmaf(c, siH.x, -s * srL.x);
    imH.y = fmaf(c, siH.y, -s * srL.y);
    imH.z = fmaf(c, siH.z, -s * srL.z);
    imH.w = fmaf(c, siH.w, -s * srL.w);

    out_re[v] = reL;
    out_re[w] = reH;
    out_im[v] = imL;
    out_im[w] = imH;
}

extern "C" void kernel_launch(void* const* d_in, const int* in_sizes, int n_in,
                              void* d_out, int out_size, void* d_ws, size_t ws_size,
                              hipStream_t stream)
{
    const float4* sr = (const float4*)d_in[0];
    const float4* si = (const float4*)d_in[1];
    const float*  th = (const float*)d_in[2];

    float4* out_re = (float4*)d_out;
    float4* out_im = out_re + ((size_t)NQ_BATCH * NQ_N / 4);

    const unsigned pairs = (unsigned)((size_t)NQ_BATCH * NQ_N / 8); // 2^21
    const unsigned block = 256;
    const unsigned grid = pairs / block;                            // 8192

    rx_butterfly_kernel<<<grid, block, 0, stream>>>(sr, si, th, out_re, out_im);
}

// Round 2
// 233.825 us; speedup vs baseline: 1.0220x; 1.0220x over previous
//
#include <hip/hip_runtime.h>
#include <math.h>

// RX gate on qubit 5 of 12, batch 4096 states of dim 4096.
// out_re[i] = c*sr[i] + s*si[i^64];  out_im[i] = c*si[i] - s*sr[i^64]
// (M = c*I - i*s*X_hyd is symmetric; X_hyd is the bit-6 flip permutation.)
//
// Streaming butterfly, memory-bound. Key layout trick: in float4-index space
// the partner is V^16. With lane l holding V = waveBase + l, the partner's
// data sits in lane l^16 of the SAME 64-lane wave -> __shfl_xor(...,16),
// so every global load/store is a fully-contiguous 1024B wave transaction.

#define NQ_N 4096
#define NQ_BATCH 4096

typedef float f32x4 __attribute__((ext_vector_type(4)));

__global__ __launch_bounds__(256)
void rx_butterfly_kernel(const f32x4* __restrict__ sr,
                         const f32x4* __restrict__ si,
                         const float* __restrict__ theta_p,
                         f32x4* __restrict__ out_re,
                         f32x4* __restrict__ out_im)
{
    const float half = 0.5f * theta_p[0];
    const float c = cosf(half);
    const float s = sinf(half);

    const unsigned t = blockIdx.x * blockDim.x + threadIdx.x; // float4 index

    const f32x4 r = sr[t];
    const f32x4 m = si[t];

    // partner lane: lane ^ 16 (bit 4 of the float4 index lives in the lane id)
    f32x4 rp, mp;
    rp.x = __shfl_xor(r.x, 16);
    rp.y = __shfl_xor(r.y, 16);
    rp.z = __shfl_xor(r.z, 16);
    rp.w = __shfl_xor(r.w, 16);
    mp.x = __shfl_xor(m.x, 16);
    mp.y = __shfl_xor(m.y, 16);
    mp.z = __shfl_xor(m.z, 16);
    mp.w = __shfl_xor(m.w, 16);

    f32x4 ore, oim;
    ore.x = fmaf(c, r.x, s * mp.x);
    ore.y = fmaf(c, r.y, s * mp.y);
    ore.z = fmaf(c, r.z, s * mp.z);
    ore.w = fmaf(c, r.w, s * mp.w);
    oim.x = fmaf(c, m.x, -s * rp.x);
    oim.y = fmaf(c, m.y, -s * rp.y);
    oim.z = fmaf(c, m.z, -s * rp.z);
    oim.w = fmaf(c, m.w, -s * rp.w);

    // write-once outputs: nontemporal so they don't evict L3-warm inputs
    __builtin_nontemporal_store(ore, out_re + t);
    __builtin_nontemporal_store(oim, out_im + t);
}

extern "C" void kernel_launch(void* const* d_in, const int* in_sizes, int n_in,
                              void* d_out, int out_size, void* d_ws, size_t ws_size,
                              hipStream_t stream)
{
    const f32x4* sr = (const f32x4*)d_in[0];
    const f32x4* si = (const f32x4*)d_in[1];
    const float* th = (const float*)d_in[2];

    f32x4* out_re = (f32x4*)d_out;
    f32x4* out_im = out_re + ((size_t)NQ_BATCH * NQ_N / 4);

    const unsigned vecs = (unsigned)((size_t)NQ_BATCH * NQ_N / 4); // 2^22
    const unsigned block = 256;
    const unsigned grid = vecs / block;                            // 16384

    rx_butterfly_kernel<<<grid, block, 0, stream>>>(sr, si, th, out_re, out_im);
}